// Round 6
// baseline (597.165 us; speedup 1.0000x reference)
//
#include <hip/hip_runtime.h>
#include <hip/hip_fp16.h>
#include <math.h>

// ---------------------------------------------------------------------------
// fp16 A2B1-split MFMA GRU pipeline, 2-blocks/CU @ 2-waves/SIMD edition,
// with LICM-blocking weight-pointer launder (R2 technique).
// 512 blocks x 256 threads (4 waves). wave w = layer l; each wave computes
// BOTH j-halves (128 AGPR accumulators: 2 jh x {Cr,Cz,Ci,Ch}).
// 32 rows/block; LDS 74.5 KiB -> 2 blocks/CU co-resident, 2 waves/SIMD,
// 256 unified regs/wave (128 arch + 128 acc), spill-free IF the in-loop
// weight loads are NOT hoisted -- hence the per-iteration asm launder of
// the g_wfrag base pointer (keeps them L2 streams, ~14 KB/block/iter).
// h-state in LDS as fp16 hi/lo chunk planes (16B granules), XOR-swizzled.
// ---------------------------------------------------------------------------

typedef __attribute__((ext_vector_type(8))) _Float16 f16x8;
typedef __attribute__((ext_vector_type(16))) float f32x16;
typedef __attribute__((ext_vector_type(4))) unsigned int u32x4;

#define NFRAG 168
__device__ __align__(16) unsigned int g_wfrag[NFRAG * 256];

#define SMEM_U32 18624
#define SEL_OFF  16384   // f32 [32][68]
#define V0_OFF   18560   // f32 [2][32]

__device__ __forceinline__ float sigm(float v) {
    return __fdividef(1.f, 1.f + __expf(-v));
}
__device__ __forceinline__ float tanhfast(float v) {
    return 1.f - __fdividef(2.f, __expf(2.f * v) + 1.f);
}
__device__ __forceinline__ f32x16 zero16() {
    f32x16 z;
    #pragma unroll
    for (int i = 0; i < 16; ++i) z[i] = 0.f;
    return z;
}

// --------------------------- weight prep kernel ----------------------------
// frag id: layers 1-3: lm1*48 + m*24 + g*8 + jh*4 + kt   (m: 0=ih, 1=hh)
//          layer 0 hh: 144 + g*8 + jh*4 + kt
// lane element: 8 fp16 = W[g*64 + jh*32 + (lane&31)][kt*16 + 8*(lane>>5) + e]
__global__ void prep_wfrag(const float* __restrict__ whh0,
                           const float* __restrict__ wihs,
                           const float* __restrict__ whhs) {
    const int gid  = blockIdx.x * 256 + threadIdx.x;
    const int frag = gid >> 6;
    const int lane = gid & 63;
    if (frag >= NFRAG) return;
    int kt, jh, g;
    const float* W;
    if (frag < 144) {
        int f = frag;
        kt = f & 3; f >>= 2;
        jh = f & 1; f >>= 1;
        g = f % 3; f /= 3;
        const int m = f & 1; f >>= 1;           // f is now lm1 (0..2)
        W = (m == 0) ? (wihs + f * 192 * 64) : (whhs + f * 192 * 64);
    } else {
        int f = frag - 144;
        kt = f & 3; f >>= 2;
        jh = f & 1; f >>= 1;
        g = f;
        W = whh0;
    }
    const int j  = g * 64 + jh * 32 + (lane & 31);
    const int k0 = kt * 16 + 8 * (lane >> 5);
    unsigned int ov[4];
    #pragma unroll
    for (int i2 = 0; i2 < 4; ++i2) {
        const unsigned short p0 = __half_as_ushort(__float2half(W[j * 64 + k0 + 2 * i2]));
        const unsigned short p1 = __half_as_ushort(__float2half(W[j * 64 + k0 + 2 * i2 + 1]));
        ov[i2] = (unsigned int)p0 | ((unsigned int)p1 << 16);
    }
    u32x4 o; o[0] = ov[0]; o[1] = ov[1]; o[2] = ov[2]; o[3] = ov[3];
    *reinterpret_cast<u32x4*>(&g_wfrag[(frag * 64 + lane) * 4]) = o;
}

// ------------------------------- helpers -----------------------------------
__device__ __forceinline__ f16x8 load_bp(const unsigned int* gw, int id, int lane) {
    return __builtin_bit_cast(f16x8,
        *reinterpret_cast<const u32x4*>(&gw[(id * 64 + lane) * 4]));
}
// read one 16B A-granule: row's chunk c (0..7 hi-plane, 8..15 lo-plane),
// XOR-swizzled by row&15 over the 16 chunks of the 256B row.
__device__ __forceinline__ f16x8 read_frag(const unsigned int* buf, int row, int c) {
    return __builtin_bit_cast(f16x8, *reinterpret_cast<const u32x4*>(
        buf + row * 64 + ((c ^ (row & 15)) << 2)));
}
#define MFMA16(C, A, B) C = __builtin_amdgcn_mfma_f32_32x32x16_f16(A, B, C, 0, 0, 0)

// ------------------------------- main kernel -------------------------------
__global__ __launch_bounds__(256, 2)
void gru_mfma(const float* __restrict__ x,       // [4][24][4096]
              const int*   __restrict__ lengths, // [4]
              const float* __restrict__ sf3,     // [3]
              const float* __restrict__ bp3,     // [3]
              const float* __restrict__ wih0,    // [192]
              const float* __restrict__ bih0,    // [192]
              const float* __restrict__ bhh0,    // [192]
              const float* __restrict__ bihs,    // [3][192]
              const float* __restrict__ bhhs,    // [3][192]
              const float* __restrict__ bng, const float* __restrict__ bnb,
              const float* __restrict__ bnm, const float* __restrict__ bnv,
              const float* __restrict__ fcW, const float* __restrict__ fcb,
              const float* __restrict__ fcWo, const float* __restrict__ fcbo,
              float* __restrict__ out) {
    __shared__ __align__(16) unsigned int smem[SMEM_U32];
    unsigned int* sm = smem;

    const int tid  = threadIdx.x;
    const int lane = tid & 63;
    const int w    = tid >> 6;                  // 0..3
    const int l    = w;                         // layer
    const int hl   = lane >> 5;
    const int ln31 = lane & 31;
    const int bid  = blockIdx.x;
    const int n    = bid >> 7;
    const int vox  = ((bid & 127) << 5) + ln31;
    const int lv   = __builtin_amdgcn_readfirstlane(lengths[n]);

    float* selF = (float*)(sm + SEL_OFF);
    float* v0F  = (float*)(sm + V0_OFF);

    for (int idx = tid; idx < SMEM_U32; idx += 256) sm[idx] = 0u;
    __syncthreads();
    if (w == 0 && lane < 32) {
        const float xv = x[(n * 24 + 0) * 4096 + vox];
        v0F[ln31] = fmaf(xv, sf3[0], bp3[0]);
    }
    __syncthreads();

    // per-wave uniform constants, both j-halves
    const float* bi = (l == 0) ? bih0 : (bihs + (l - 1) * 192);
    const float* bh = (l == 0) ? bhh0 : (bhhs + (l - 1) * 192);
    const int jc0 = ln31;
    const int jc1 = 32 + ln31;
    const float biasr0 = bi[jc0] + bh[jc0],        biasr1 = bi[jc1] + bh[jc1];
    const float biasz0 = bi[64 + jc0] + bh[64 + jc0], biasz1 = bi[64 + jc1] + bh[64 + jc1];
    const float biasni0 = bi[128 + jc0],           biasni1 = bi[128 + jc1];
    const float biasnh0 = bh[128 + jc0],           biasnh1 = bh[128 + jc1];
    float w0r0 = 0.f, w0z0 = 0.f, w0n0 = 0.f, w0r1 = 0.f, w0z1 = 0.f, w0n1 = 0.f;
    if (l == 0) {
        w0r0 = wih0[jc0]; w0z0 = wih0[64 + jc0]; w0n0 = wih0[128 + jc0];
        w0r1 = wih0[jc1]; w0z1 = wih0[64 + jc1]; w0n1 = wih0[128 + jc1];
    }
    const int ihB0 = (l - 1) * 48;                       // l>0 only
    const int ihB1 = ihB0 + 4;
    const int hhB0 = (l == 0) ? 144 : (ihB0 + 24);
    const int hhB1 = (l == 0) ? 148 : (ihB1 + 24);

    // write addressing (jh=0 base; jh=1 is iHi ^ 32 since chw(jh1)=chw+4)
    const int chw = jc0 >> 3, wrd = (jc0 & 7) >> 1, hv = jc0 & 1;

    // h(t-1) for this lane's C-fragment cells, fp32 (jh*16 + rg)
    float hreg[32];
    #pragma unroll
    for (int q = 0; q < 32; ++q) hreg[q] = 0.f;

    // ---------------- pipelined GRU layers ----------------
    for (int i = 0; i <= lv + 2; ++i) {
        const int t = i - l;
        // next-t x prefetch (wave 0, 32 lanes)
        if (w == 0 && lane < 32) {
            const int tn = i + 1;
            if (tn < lv) {
                const int r3 = tn % 3;
                const float xv = x[(n * 24 + tn) * 4096 + vox];
                v0F[(tn & 1) * 32 + ln31] = fmaf(xv, sf3[r3], bp3[r3]);
            }
        }
        if (t >= 0 && t < lv) {
            // launder the weight base pointer each iteration: blocks LICM
            // from hoisting the loop-invariant weight loads into ~96 regs
            // (which spilled in R5: FETCH 190 MB of scratch reloads).
            const unsigned int* gw = g_wfrag;
            asm volatile("" : "+s"(gw));

            const int pbit = t & 1;
            const unsigned int* hOwn = sm + l * 4096 + (pbit ^ 1) * 2048;
            const unsigned int* hUp  = (l > 0) ? (sm + (l - 1) * 4096 + pbit * 2048) : nullptr;
            unsigned short* hw16 = (unsigned short*)(sm + l * 4096 + pbit * 2048);
            const bool dosel = (l == 3) && (t == lv - 1 || t == lv - 4);

            f32x16 Cr0 = zero16(), Cz0 = zero16(), Ci0 = zero16(), Ch0 = zero16();
            f32x16 Cr1 = zero16(), Cz1 = zero16(), Ci1 = zero16(), Ch1 = zero16();

            __builtin_amdgcn_s_setprio(1);
            #pragma unroll
            for (int kt = 0; kt < 4; ++kt) {
                const int cH = 2 * kt + hl;
                // A fragments read ONCE, reused by both jh
                const f16x8 ah_h = read_frag(hOwn, ln31, cH);
                const f16x8 ah_l = read_frag(hOwn, ln31, cH | 8);
                // jh = 0
                {
                    const f16x8 Brh = load_bp(gw, hhB0 + 0  + kt, lane);
                    const f16x8 Bzh = load_bp(gw, hhB0 + 8  + kt, lane);
                    const f16x8 Bnh = load_bp(gw, hhB0 + 16 + kt, lane);
                    MFMA16(Cr0, ah_h, Brh); MFMA16(Cr0, ah_l, Brh);
                    MFMA16(Cz0, ah_h, Bzh); MFMA16(Cz0, ah_l, Bzh);
                    MFMA16(Ch0, ah_h, Bnh); MFMA16(Ch0, ah_l, Bnh);
                }
                // jh = 1
                {
                    const f16x8 Brh = load_bp(gw, hhB1 + 0  + kt, lane);
                    const f16x8 Bzh = load_bp(gw, hhB1 + 8  + kt, lane);
                    const f16x8 Bnh = load_bp(gw, hhB1 + 16 + kt, lane);
                    MFMA16(Cr1, ah_h, Brh); MFMA16(Cr1, ah_l, Brh);
                    MFMA16(Cz1, ah_h, Bzh); MFMA16(Cz1, ah_l, Bzh);
                    MFMA16(Ch1, ah_h, Bnh); MFMA16(Ch1, ah_l, Bnh);
                }
                if (l > 0) {
                    const f16x8 ax_h = read_frag(hUp, ln31, cH);
                    const f16x8 ax_l = read_frag(hUp, ln31, cH | 8);
                    {
                        const f16x8 Bri = load_bp(gw, ihB0 + 0  + kt, lane);
                        const f16x8 Bzi = load_bp(gw, ihB0 + 8  + kt, lane);
                        const f16x8 Bni = load_bp(gw, ihB0 + 16 + kt, lane);
                        MFMA16(Cr0, ax_h, Bri); MFMA16(Cr0, ax_l, Bri);
                        MFMA16(Cz0, ax_h, Bzi); MFMA16(Cz0, ax_l, Bzi);
                        MFMA16(Ci0, ax_h, Bni); MFMA16(Ci0, ax_l, Bni);
                    }
                    {
                        const f16x8 Bri = load_bp(gw, ihB1 + 0  + kt, lane);
                        const f16x8 Bzi = load_bp(gw, ihB1 + 8  + kt, lane);
                        const f16x8 Bni = load_bp(gw, ihB1 + 16 + kt, lane);
                        MFMA16(Cr1, ax_h, Bri); MFMA16(Cr1, ax_l, Bri);
                        MFMA16(Cz1, ax_h, Bzi); MFMA16(Cz1, ax_l, Bzi);
                        MFMA16(Ci1, ax_h, Bni); MFMA16(Ci1, ax_l, Bni);
                    }
                }
            }
            __builtin_amdgcn_s_setprio(0);

            // extract + h update (C layout: col=lane&31, row=(rg&3)+8*(rg>>2)+4*hl)
            #pragma unroll
            for (int jh = 0; jh < 2; ++jh) {
                #pragma unroll
                for (int rg = 0; rg < 16; ++rg) {
                    const int row = (rg & 3) + ((rg >> 2) << 3) + (hl << 2);
                    const int rsw = row & 15;
                    const int iH0 = row * 128 + (((chw ^ rsw) << 2) + wrd) * 2 + hv;
                    const int iHi = jh ? (iH0 ^ 32) : iH0;
                    const int iLo = iHi ^ 64;
                    float pr = (jh ? Cr1[rg] : Cr0[rg]) + (jh ? biasr1 : biasr0);
                    float pz = (jh ? Cz1[rg] : Cz0[rg]) + (jh ? biasz1 : biasz0);
                    float ph = (jh ? Ch1[rg] : Ch0[rg]) + (jh ? biasnh1 : biasnh0);
                    float pi = (jh ? Ci1[rg] : Ci0[rg]) + (jh ? biasni1 : biasni0);
                    if (l == 0) {
                        const float v0 = v0F[pbit * 32 + row];
                        pr = fmaf(v0, jh ? w0r1 : w0r0, pr);
                        pz = fmaf(v0, jh ? w0z1 : w0z0, pz);
                        pi = fmaf(v0, jh ? w0n1 : w0n0, pi);
                    }
                    const float r  = sigm(pr);
                    const float z  = sigm(pz);
                    const float nn = tanhfast(fmaf(r, ph, pi));
                    const float hp = hreg[jh * 16 + rg];
                    const float hn = fmaf(z, hp - nn, nn);
                    hreg[jh * 16 + rg] = hn;
                    const __half hhi = __float2half(hn);
                    hw16[iHi] = __half_as_ushort(hhi);
                    hw16[iLo] = __half_as_ushort(__float2half(hn - __half2float(hhi)));
                    if (dosel) selF[row * 68 + jh * 32 + ln31] += hn;
                }
            }
        }
        __syncthreads();
    }

    // ---------------- MLP head: 4 waves x 64 lanes, 8 cols each ----------------
    float* ybuf = (float*)sm;             // [32][68]
    float* psum = (float*)sm + 32 * 68;   // [4][64]
    const int jb  = w * 16 + hl * 8;
    const int row = ln31;
    float h2[8];
    #pragma unroll
    for (int jj = 0; jj < 8; ++jj) h2[jj] = selF[row * 68 + jb + jj];

    for (int li = 0; li < 5; ++li) {
        __syncthreads();
        #pragma unroll
        for (int jj = 0; jj < 8; ++jj) {
            const int j = jb + jj;
            const float sc = bng[li * 64 + j] * rsqrtf(bnv[li * 64 + j] + 1e-5f);
            const float y  = fmaf(h2[jj] - bnm[li * 64 + j], sc, bnb[li * 64 + j]);
            ybuf[row * 68 + j] = y * sigm(y);
        }
        __syncthreads();
        #pragma unroll
        for (int jj = 0; jj < 8; ++jj) {
            const int j = jb + jj;
            float acc = fcb[li * 64 + j];
            const float* wr = fcW + (li * 64 + j) * 64;
            #pragma unroll
            for (int k = 0; k < 64; k += 4) {
                const float4 yv = *reinterpret_cast<const float4*>(ybuf + row * 68 + k);
                acc = fmaf(yv.x, wr[k],     acc);
                acc = fmaf(yv.y, wr[k + 1], acc);
                acc = fmaf(yv.z, wr[k + 2], acc);
                acc = fmaf(yv.w, wr[k + 3], acc);
            }
            h2[jj] = acc;
        }
    }
    {
        float part = 0.f;
        #pragma unroll
        for (int jj = 0; jj < 8; ++jj) {
            const int j = jb + jj;
            const float sc = bng[5 * 64 + j] * rsqrtf(bnv[5 * 64 + j] + 1e-5f);
            const float y  = fmaf(h2[jj] - bnm[5 * 64 + j], sc, bnb[5 * 64 + j]);
            part = fmaf(y * sigm(y), fcWo[j], part);
        }
        psum[w * 64 + lane] = part;
    }
    __syncthreads();
    if (w == 0 && lane < 32) {
        float s = fcbo[0];
        #pragma unroll
        for (int q = 0; q < 4; ++q) s += psum[q * 64 + row] + psum[q * 64 + row + 32];
        out[(bid << 5) + row] = s;
    }
}

extern "C" void kernel_launch(void* const* d_in, const int* in_sizes, int n_in,
                              void* d_out, int out_size, void* d_ws, size_t ws_size,
                              hipStream_t stream) {
    (void)in_sizes; (void)n_in; (void)d_ws; (void)ws_size; (void)out_size;
    const float* x    = (const float*)d_in[0];
    const int*   len  = (const int*)d_in[1];
    const float* sf3  = (const float*)d_in[2];
    const float* bp3  = (const float*)d_in[3];
    const float* wih0 = (const float*)d_in[4];
    const float* whh0 = (const float*)d_in[5];
    const float* bih0 = (const float*)d_in[6];
    const float* bhh0 = (const float*)d_in[7];
    const float* wihs = (const float*)d_in[8];
    const float* whhs = (const float*)d_in[9];
    const float* bihs = (const float*)d_in[10];
    const float* bhhs = (const float*)d_in[11];
    const float* bng  = (const float*)d_in[12];
    const float* bnb  = (const float*)d_in[13];
    const float* bnm  = (const float*)d_in[14];
    const float* bnv  = (const float*)d_in[15];
    const float* fcW  = (const float*)d_in[16];
    const float* fcb  = (const float*)d_in[17];
    const float* fcWo = (const float*)d_in[18];
    const float* fcbo = (const float*)d_in[19];
    float* out = (float*)d_out;

    prep_wfrag<<<dim3(42), dim3(256), 0, stream>>>(whh0, wihs, whhs);
    gru_mfma<<<dim3(512), dim3(256), 0, stream>>>(
        x, len, sf3, bp3, wih0, bih0, bhh0, bihs, bhhs,
        bng, bnb, bnm, bnv, fcW, fcb, fcWo, fcbo, out);
}

// Round 7
// 391.147 us; speedup vs baseline: 1.5267x; 1.5267x over previous
//
#include <hip/hip_runtime.h>
#include <hip/hip_fp16.h>
#include <math.h>

// ---------------------------------------------------------------------------
// fp16 A2B1-split MFMA GRU pipeline, R0 skeleton + full weight preload.
// 256 blocks x 512 threads (8 waves). wave w -> (layer l=w>>1, jhalf=w&1).
// 64 rows/block; layers pipelined in time (wave l works on t = i - l).
// h-state in LDS as fp16 hi-chunks + lo-chunks (16B granules), XOR-swizzled.
// Row-tiles processed SEQUENTIALLY (64 accum regs); h(t-1) in hreg.
// R7 changes vs R0 (verified 406 us):
//  - Bih[12] preloaded to registers like Bhh (l>0): ZERO in-loop VMEM in the
//    recurrence for l>0 waves. 96 weight regs + 64 acc + rest = ~240 <= 256.
//  - main-loop barrier drains lgkmcnt only (no vmcnt(0) drain).
//  - wave-0 x input rotated through a register (consumed next iteration).
// Extract math, LDS layout, zero16 acc init: byte-identical to R0.
// ---------------------------------------------------------------------------

typedef __attribute__((ext_vector_type(8))) _Float16 f16x8;
typedef __attribute__((ext_vector_type(16))) float f32x16;
typedef __attribute__((ext_vector_type(4))) unsigned int u32x4;

#define NFRAG 168
__device__ __align__(16) unsigned int g_wfrag[NFRAG * 256];

#define SMEM_U32 37248
#define SEL_OFF  32768   // f32 [64][68]
#define V0_OFF   37120   // f32 [2][64]

__device__ __forceinline__ float sigm(float v) {
    return __fdividef(1.f, 1.f + __expf(-v));
}
__device__ __forceinline__ float tanhfast(float v) {
    return 1.f - __fdividef(2.f, __expf(2.f * v) + 1.f);
}
__device__ __forceinline__ f32x16 zero16() {
    f32x16 z;
    #pragma unroll
    for (int i = 0; i < 16; ++i) z[i] = 0.f;
    return z;
}

// light block barrier: LDS-producer drain only, no vmcnt(0) drain.
#define BLOCK_SYNC() do {                                   \
    asm volatile("s_waitcnt lgkmcnt(0)" ::: "memory");      \
    __builtin_amdgcn_s_barrier();                           \
    __builtin_amdgcn_sched_barrier(0);                      \
} while (0)

// --------------------------- weight prep kernel ----------------------------
// frag id: layers 1-3: lm1*48 + m*24 + g*8 + jh*4 + kt   (m: 0=ih, 1=hh)
//          layer 0 hh: 144 + g*8 + jh*4 + kt
// lane element: 8 fp16 = W[g*64 + jh*32 + (lane&31)][kt*16 + 8*(lane>>5) + e]
__global__ void prep_wfrag(const float* __restrict__ whh0,
                           const float* __restrict__ wihs,
                           const float* __restrict__ whhs) {
    const int gid  = blockIdx.x * 256 + threadIdx.x;
    const int frag = gid >> 6;
    const int lane = gid & 63;
    if (frag >= NFRAG) return;
    int kt, jh, g;
    const float* W;
    if (frag < 144) {
        int f = frag;
        kt = f & 3; f >>= 2;
        jh = f & 1; f >>= 1;
        g = f % 3; f /= 3;
        const int m = f & 1; f >>= 1;           // f is now lm1 (0..2)
        W = (m == 0) ? (wihs + f * 192 * 64) : (whhs + f * 192 * 64);
    } else {
        int f = frag - 144;
        kt = f & 3; f >>= 2;
        jh = f & 1; f >>= 1;
        g = f;
        W = whh0;
    }
    const int j  = g * 64 + jh * 32 + (lane & 31);
    const int k0 = kt * 16 + 8 * (lane >> 5);
    unsigned int ov[4];
    #pragma unroll
    for (int i2 = 0; i2 < 4; ++i2) {
        const unsigned short p0 = __half_as_ushort(__float2half(W[j * 64 + k0 + 2 * i2]));
        const unsigned short p1 = __half_as_ushort(__float2half(W[j * 64 + k0 + 2 * i2 + 1]));
        ov[i2] = (unsigned int)p0 | ((unsigned int)p1 << 16);
    }
    u32x4 o; o[0] = ov[0]; o[1] = ov[1]; o[2] = ov[2]; o[3] = ov[3];
    *reinterpret_cast<u32x4*>(&g_wfrag[(frag * 64 + lane) * 4]) = o;
}

// ------------------------------- helpers -----------------------------------
__device__ __forceinline__ f16x8 load_b(int id, int lane) {
    return __builtin_bit_cast(f16x8,
        *reinterpret_cast<const u32x4*>(&g_wfrag[(id * 64 + lane) * 4]));
}
// read one 16B A-granule: row's chunk c (0..7 hi-plane, 8..15 lo-plane),
// XOR-swizzled by row&15 over the 16 chunks of the 256B row.
__device__ __forceinline__ f16x8 read_frag(const unsigned int* buf, int row, int c) {
    return __builtin_bit_cast(f16x8, *reinterpret_cast<const u32x4*>(
        buf + row * 64 + ((c ^ (row & 15)) << 2)));
}
#define MFMA16(C, A, B) C = __builtin_amdgcn_mfma_f32_32x32x16_f16(A, B, C, 0, 0, 0)

// ------------------------------- main kernel -------------------------------
__global__ __launch_bounds__(512, 2)
void gru_mfma(const float* __restrict__ x,       // [4][24][4096]
              const int*   __restrict__ lengths, // [4]
              const float* __restrict__ sf3,     // [3]
              const float* __restrict__ bp3,     // [3]
              const float* __restrict__ wih0,    // [192]
              const float* __restrict__ bih0,    // [192]
              const float* __restrict__ bhh0,    // [192]
              const float* __restrict__ bihs,    // [3][192]
              const float* __restrict__ bhhs,    // [3][192]
              const float* __restrict__ bng, const float* __restrict__ bnb,
              const float* __restrict__ bnm, const float* __restrict__ bnv,
              const float* __restrict__ fcW, const float* __restrict__ fcb,
              const float* __restrict__ fcWo, const float* __restrict__ fcbo,
              float* __restrict__ out) {
    __shared__ __align__(16) unsigned int smem[SMEM_U32];
    unsigned int* sm = smem;

    const int tid  = threadIdx.x;
    const int lane = tid & 63;
    const int w    = tid >> 6;                  // 0..7
    const int l    = w >> 1;                    // layer
    const int jh   = w & 1;                     // j-half
    const int hl   = lane >> 5;
    const int ln31 = lane & 31;
    const int bid  = blockIdx.x;
    const int n    = bid >> 6;
    const int vox  = ((bid & 63) << 6) + lane;
    const int lv   = __builtin_amdgcn_readfirstlane(lengths[n]);

    float* selF = (float*)(sm + SEL_OFF);
    float* v0F  = (float*)(sm + V0_OFF);

    for (int idx = tid; idx < SMEM_U32; idx += 512) sm[idx] = 0u;
    __syncthreads();

    // layer-0 input rotation state (wave 0 is the sole producer of v0F)
    const float s0 = sf3[0], s1 = sf3[1], s2 = sf3[2];
    const float b0 = bp3[0], b1 = bp3[1], b2 = bp3[2];
    float xv = 0.f;
    int r3 = 1;                                  // (i+1) % 3 rotation
    if (w == 0) {
        const float x0 = x[(n * 24 + 0) * 4096 + vox];
        v0F[lane] = fmaf(x0, s0, b0);            // t = 0, buffer 0
        if (lv > 1) xv = x[(n * 24 + 1) * 4096 + vox];   // issue t=1 load
    }
    __syncthreads();

    // per-wave uniform constants
    const float* bi = (l == 0) ? bih0 : (bihs + (l - 1) * 192);
    const float* bh = (l == 0) ? bhh0 : (bhhs + (l - 1) * 192);
    const int jc = jh * 32 + ln31;
    const float biasr  = bi[jc] + bh[jc];
    const float biasz  = bi[64 + jc] + bh[64 + jc];
    const float biasni = bi[128 + jc];
    const float biasnh = bh[128 + jc];
    float w0r = 0.f, w0z = 0.f, w0n = 0.f;
    if (l == 0) { w0r = wih0[jc]; w0z = wih0[64 + jc]; w0n = wih0[128 + jc]; }
    const int ihB = (l - 1) * 48 + jh * 4;                     // l>0 only
    const int hhB = (l == 0) ? (144 + jh * 4) : (ihB + 24);
    const int ihBase = (l == 0) ? hhB : ihB;     // harmless alias for l==0

    // preload ALL weight fragments (loop-invariant, 96 VGPRs):
    // hh always used; ih used only by l>0 (l==0 loads hh again, dead values).
    f16x8 Bhh[12], Bih[12];
    #pragma unroll
    for (int g = 0; g < 3; ++g)
        #pragma unroll
        for (int kt = 0; kt < 4; ++kt) {
            Bhh[g * 4 + kt] = load_b(hhB + g * 8 + kt, lane);
            Bih[g * 4 + kt] = load_b(ihBase + g * 8 + kt, lane);
        }

    // write addressing for this lane's column jc
    const int chw = jc >> 3, wrd = (jc & 7) >> 1, hv = jc & 1;

    // h(t-1) for this lane's C-fragment cells, fp32
    float hreg[32];
    #pragma unroll
    for (int q = 0; q < 32; ++q) hreg[q] = 0.f;

    // ---------------- pipelined GRU layers ----------------
    for (int i = 0; i <= lv + 2; ++i) {
        const int t = i - l;
        // layer-0 input: consume last iteration's load, issue the next one.
        if (w == 0) {
            const int tn = i + 1;
            if (tn < lv) {
                const float sfc = (r3 == 0) ? s0 : ((r3 == 1) ? s1 : s2);
                const float bpc = (r3 == 0) ? b0 : ((r3 == 1) ? b1 : b2);
                v0F[(tn & 1) * 64 + lane] = fmaf(xv, sfc, bpc);
                r3 = (r3 == 2) ? 0 : r3 + 1;
                if (tn + 1 < lv) xv = x[(n * 24 + tn + 1) * 4096 + vox];
            }
        }
        if (t >= 0 && t < lv) {
            const int pbit = t & 1;
            const unsigned int* hOwn = sm + l * 8192 + (pbit ^ 1) * 4096;
            const unsigned int* hUp  = (l > 0) ? (sm + (l - 1) * 8192 + pbit * 4096) : nullptr;
            unsigned short* hw16 = (unsigned short*)(sm + l * 8192 + pbit * 4096);
            const bool dosel = (l == 3) && (t == lv - 1 || t == lv - 4);

            #pragma unroll
            for (int rt = 0; rt < 2; ++rt) {
                const int rb = rt * 32;
                f32x16 Cr = zero16(), Cz = zero16(), Ci = zero16(), Ch = zero16();

                __builtin_amdgcn_s_setprio(1);
                #pragma unroll
                for (int kt = 0; kt < 4; ++kt) {
                    const int cH = 2 * kt + hl;
                    const f16x8 ah_h = read_frag(hOwn, rb + ln31, cH);
                    const f16x8 ah_l = read_frag(hOwn, rb + ln31, cH | 8);
                    MFMA16(Cr, ah_h, Bhh[kt]);     MFMA16(Cr, ah_l, Bhh[kt]);
                    MFMA16(Cz, ah_h, Bhh[4 + kt]); MFMA16(Cz, ah_l, Bhh[4 + kt]);
                    MFMA16(Ch, ah_h, Bhh[8 + kt]); MFMA16(Ch, ah_l, Bhh[8 + kt]);
                    if (l > 0) {
                        const f16x8 ax_h = read_frag(hUp, rb + ln31, cH);
                        const f16x8 ax_l = read_frag(hUp, rb + ln31, cH | 8);
                        MFMA16(Cr, ax_h, Bih[kt]);     MFMA16(Cr, ax_l, Bih[kt]);
                        MFMA16(Cz, ax_h, Bih[4 + kt]); MFMA16(Cz, ax_l, Bih[4 + kt]);
                        MFMA16(Ci, ax_h, Bih[8 + kt]); MFMA16(Ci, ax_l, Bih[8 + kt]);
                    }
                }
                __builtin_amdgcn_s_setprio(0);

                // extract + h update (C layout: col=lane&31, row=(rg&3)+8*(rg>>2)+4*hl)
                #pragma unroll
                for (int rg = 0; rg < 16; ++rg) {
                    const int row = rb + (rg & 3) + ((rg >> 2) << 3) + (hl << 2);
                    const int rsw = row & 15;
                    const int iHi = row * 128 + (((chw ^ rsw) << 2) + wrd) * 2 + hv;
                    const int iLo = iHi ^ 64;
                    float pr = Cr[rg] + biasr;
                    float pz = Cz[rg] + biasz;
                    float pi = Ci[rg] + biasni;
                    float ph = Ch[rg] + biasnh;
                    if (l == 0) {
                        const float v0 = v0F[pbit * 64 + row];
                        pr = fmaf(v0, w0r, pr);
                        pz = fmaf(v0, w0z, pz);
                        pi = fmaf(v0, w0n, pi);
                    }
                    const float r  = sigm(pr);
                    const float z  = sigm(pz);
                    const float nn = tanhfast(fmaf(r, ph, pi));
                    const float hp = hreg[rt * 16 + rg];
                    const float hn = fmaf(z, hp - nn, nn);
                    hreg[rt * 16 + rg] = hn;
                    const __half hhi = __float2half(hn);
                    hw16[iHi] = __half_as_ushort(hhi);
                    hw16[iLo] = __half_as_ushort(__float2half(hn - __half2float(hhi)));
                    if (dosel) selF[row * 68 + jc] += hn;
                }
                __builtin_amdgcn_sched_barrier(0);   // keep tiles sequential (reg pressure)
            }
        }
        BLOCK_SYNC();
    }

    __syncthreads();

    // ---------------- MLP head: 8 waves, 8 cols each ----------------
    float* ybuf = (float*)sm;             // [64][68]
    float* psum = (float*)sm + 64 * 68;   // [8][64]
    const int jb = w * 8;
    float h2[8];
    #pragma unroll
    for (int jj = 0; jj < 8; ++jj) h2[jj] = selF[lane * 68 + jb + jj];

    for (int li = 0; li < 5; ++li) {
        __syncthreads();
        #pragma unroll
        for (int jj = 0; jj < 8; ++jj) {
            const int j = jb + jj;
            const float sc = bng[li * 64 + j] * rsqrtf(bnv[li * 64 + j] + 1e-5f);
            const float y  = fmaf(h2[jj] - bnm[li * 64 + j], sc, bnb[li * 64 + j]);
            ybuf[lane * 68 + j] = y * sigm(y);
        }
        __syncthreads();
        #pragma unroll
        for (int jj = 0; jj < 8; ++jj) {
            const int j = jb + jj;
            float acc = fcb[li * 64 + j];
            const float* wr = fcW + (li * 64 + j) * 64;
            #pragma unroll
            for (int k = 0; k < 64; k += 4) {
                const float4 yv = *reinterpret_cast<const float4*>(ybuf + lane * 68 + k);
                acc = fmaf(yv.x, wr[k],     acc);
                acc = fmaf(yv.y, wr[k + 1], acc);
                acc = fmaf(yv.z, wr[k + 2], acc);
                acc = fmaf(yv.w, wr[k + 3], acc);
            }
            h2[jj] = acc;
        }
    }
    {
        float part = 0.f;
        #pragma unroll
        for (int jj = 0; jj < 8; ++jj) {
            const int j = jb + jj;
            const float sc = bng[5 * 64 + j] * rsqrtf(bnv[5 * 64 + j] + 1e-5f);
            const float y  = fmaf(h2[jj] - bnm[5 * 64 + j], sc, bnb[5 * 64 + j]);
            part = fmaf(y * sigm(y), fcWo[j], part);
        }
        psum[w * 64 + lane] = part;
    }
    __syncthreads();
    if (w == 0) {
        float s = fcbo[0];
        #pragma unroll
        for (int q = 0; q < 8; ++q) s += psum[q * 64 + lane];
        out[(bid << 6) + lane] = s;
    }
}

extern "C" void kernel_launch(void* const* d_in, const int* in_sizes, int n_in,
                              void* d_out, int out_size, void* d_ws, size_t ws_size,
                              hipStream_t stream) {
    (void)in_sizes; (void)n_in; (void)d_ws; (void)ws_size; (void)out_size;
    const float* x    = (const float*)d_in[0];
    const int*   len  = (const int*)d_in[1];
    const float* sf3  = (const float*)d_in[2];
    const float* bp3  = (const float*)d_in[3];
    const float* wih0 = (const float*)d_in[4];
    const float* whh0 = (const float*)d_in[5];
    const float* bih0 = (const float*)d_in[6];
    const float* bhh0 = (const float*)d_in[7];
    const float* wihs = (const float*)d_in[8];
    const float* whhs = (const float*)d_in[9];
    const float* bihs = (const float*)d_in[10];
    const float* bhhs = (const float*)d_in[11];
    const float* bng  = (const float*)d_in[12];
    const float* bnb  = (const float*)d_in[13];
    const float* bnm  = (const float*)d_in[14];
    const float* bnv  = (const float*)d_in[15];
    const float* fcW  = (const float*)d_in[16];
    const float* fcb  = (const float*)d_in[17];
    const float* fcWo = (const float*)d_in[18];
    const float* fcbo = (const float*)d_in[19];
    float* out = (float*)d_out;

    prep_wfrag<<<dim3(42), dim3(256), 0, stream>>>(whh0, wihs, whhs);
    gru_mfma<<<dim3(256), dim3(512), 0, stream>>>(
        x, len, sf3, bp3, wih0, bih0, bhh0, bihs, bhhs,
        bng, bnb, bnm, bnv, fcW, fcb, fcWo, fcbo, out);
}

// Round 8
// 370.928 us; speedup vs baseline: 1.6099x; 1.0545x over previous
//
#include <hip/hip_runtime.h>
#include <hip/hip_fp16.h>
#include <math.h>

// ---------------------------------------------------------------------------
// fp16 A2B1-split MFMA GRU pipeline — R0 skeleton + light barrier + x-rotate.
// 256 blocks x 512 threads (8 waves). wave w -> (layer l=w>>1, jhalf=w&1).
// 64 rows/block; layers pipelined in time (wave l works on t = i - l).
// h-state in LDS as fp16 hi-chunks + lo-chunks (16B granules), XOR-swizzled.
// Row-tiles processed SEQUENTIALLY (64 accum regs); hh-weights preloaded
// (48 VGPR); ih-weights stream from L2 in-loop; h(t-1) in hreg.
// R8 = R0 + exactly two register-neutral changes (each harness-verified
// inside R4/R7 runs, here unconfounded by spills):
//  1. main-loop barrier drains lgkmcnt ONLY (no per-iteration vmcnt(0)
//     drain of in-flight x / weight loads; LDS is the only cross-wave path).
//  2. wave-0 x input rotated through a register: value loaded in iteration
//     i is consumed in iteration i+1, hiding global latency off the convoy.
// ---------------------------------------------------------------------------

typedef __attribute__((ext_vector_type(8))) _Float16 f16x8;
typedef __attribute__((ext_vector_type(16))) float f32x16;
typedef __attribute__((ext_vector_type(4))) unsigned int u32x4;

#define NFRAG 168
__device__ __align__(16) unsigned int g_wfrag[NFRAG * 256];

#define SMEM_U32 37248
#define SEL_OFF  32768   // f32 [64][68]
#define V0_OFF   37120   // f32 [2][64]

__device__ __forceinline__ float sigm(float v) {
    return __fdividef(1.f, 1.f + __expf(-v));
}
__device__ __forceinline__ float tanhfast(float v) {
    return 1.f - __fdividef(2.f, __expf(2.f * v) + 1.f);
}
__device__ __forceinline__ f32x16 zero16() {
    f32x16 z;
    #pragma unroll
    for (int i = 0; i < 16; ++i) z[i] = 0.f;
    return z;
}

// light block barrier: LDS-producer drain only, no vmcnt(0) drain.
#define BLOCK_SYNC() do {                                   \
    asm volatile("s_waitcnt lgkmcnt(0)" ::: "memory");      \
    __builtin_amdgcn_s_barrier();                           \
    __builtin_amdgcn_sched_barrier(0);                      \
} while (0)

// --------------------------- weight prep kernel ----------------------------
// frag id: layers 1-3: lm1*48 + m*24 + g*8 + jh*4 + kt   (m: 0=ih, 1=hh)
//          layer 0 hh: 144 + g*8 + jh*4 + kt
// lane element: 8 fp16 = W[g*64 + jh*32 + (lane&31)][kt*16 + 8*(lane>>5) + e]
__global__ void prep_wfrag(const float* __restrict__ whh0,
                           const float* __restrict__ wihs,
                           const float* __restrict__ whhs) {
    const int gid  = blockIdx.x * 256 + threadIdx.x;
    const int frag = gid >> 6;
    const int lane = gid & 63;
    if (frag >= NFRAG) return;
    int kt, jh, g;
    const float* W;
    if (frag < 144) {
        int f = frag;
        kt = f & 3; f >>= 2;
        jh = f & 1; f >>= 1;
        g = f % 3; f /= 3;
        const int m = f & 1; f >>= 1;           // f is now lm1 (0..2)
        W = (m == 0) ? (wihs + f * 192 * 64) : (whhs + f * 192 * 64);
    } else {
        int f = frag - 144;
        kt = f & 3; f >>= 2;
        jh = f & 1; f >>= 1;
        g = f;
        W = whh0;
    }
    const int j  = g * 64 + jh * 32 + (lane & 31);
    const int k0 = kt * 16 + 8 * (lane >> 5);
    unsigned int ov[4];
    #pragma unroll
    for (int i2 = 0; i2 < 4; ++i2) {
        const unsigned short p0 = __half_as_ushort(__float2half(W[j * 64 + k0 + 2 * i2]));
        const unsigned short p1 = __half_as_ushort(__float2half(W[j * 64 + k0 + 2 * i2 + 1]));
        ov[i2] = (unsigned int)p0 | ((unsigned int)p1 << 16);
    }
    u32x4 o; o[0] = ov[0]; o[1] = ov[1]; o[2] = ov[2]; o[3] = ov[3];
    *reinterpret_cast<u32x4*>(&g_wfrag[(frag * 64 + lane) * 4]) = o;
}

// ------------------------------- helpers -----------------------------------
__device__ __forceinline__ f16x8 load_b(int id, int lane) {
    return __builtin_bit_cast(f16x8,
        *reinterpret_cast<const u32x4*>(&g_wfrag[(id * 64 + lane) * 4]));
}
// read one 16B A-granule: row's chunk c (0..7 hi-plane, 8..15 lo-plane),
// XOR-swizzled by row&15 over the 16 chunks of the 256B row.
__device__ __forceinline__ f16x8 read_frag(const unsigned int* buf, int row, int c) {
    return __builtin_bit_cast(f16x8, *reinterpret_cast<const u32x4*>(
        buf + row * 64 + ((c ^ (row & 15)) << 2)));
}
#define MFMA16(C, A, B) C = __builtin_amdgcn_mfma_f32_32x32x16_f16(A, B, C, 0, 0, 0)

// ------------------------------- main kernel -------------------------------
__global__ __launch_bounds__(512, 2)
void gru_mfma(const float* __restrict__ x,       // [4][24][4096]
              const int*   __restrict__ lengths, // [4]
              const float* __restrict__ sf3,     // [3]
              const float* __restrict__ bp3,     // [3]
              const float* __restrict__ wih0,    // [192]
              const float* __restrict__ bih0,    // [192]
              const float* __restrict__ bhh0,    // [192]
              const float* __restrict__ bihs,    // [3][192]
              const float* __restrict__ bhhs,    // [3][192]
              const float* __restrict__ bng, const float* __restrict__ bnb,
              const float* __restrict__ bnm, const float* __restrict__ bnv,
              const float* __restrict__ fcW, const float* __restrict__ fcb,
              const float* __restrict__ fcWo, const float* __restrict__ fcbo,
              float* __restrict__ out) {
    __shared__ __align__(16) unsigned int smem[SMEM_U32];
    unsigned int* sm = smem;

    const int tid  = threadIdx.x;
    const int lane = tid & 63;
    const int w    = tid >> 6;                  // 0..7
    const int l    = w >> 1;                    // layer
    const int jh   = w & 1;                     // j-half
    const int hl   = lane >> 5;
    const int ln31 = lane & 31;
    const int bid  = blockIdx.x;
    const int n    = bid >> 6;
    const int vox  = ((bid & 63) << 6) + lane;
    const int lv   = __builtin_amdgcn_readfirstlane(lengths[n]);

    float* selF = (float*)(sm + SEL_OFF);
    float* v0F  = (float*)(sm + V0_OFF);

    for (int idx = tid; idx < SMEM_U32; idx += 512) sm[idx] = 0u;
    __syncthreads();

    // layer-0 input rotation state (wave 0 is the sole producer of v0F)
    const float s0 = sf3[0], s1 = sf3[1], s2 = sf3[2];
    const float b0 = bp3[0], b1 = bp3[1], b2 = bp3[2];
    float xv = 0.f;
    int r3 = 1;                                  // (i+1) % 3 rotation
    if (w == 0) {
        const float x0 = x[(n * 24 + 0) * 4096 + vox];
        v0F[lane] = fmaf(x0, s0, b0);            // t = 0, buffer 0
        if (lv > 1) xv = x[(n * 24 + 1) * 4096 + vox];   // issue t=1 load
    }
    __syncthreads();

    // per-wave uniform constants
    const float* bi = (l == 0) ? bih0 : (bihs + (l - 1) * 192);
    const float* bh = (l == 0) ? bhh0 : (bhhs + (l - 1) * 192);
    const int jc = jh * 32 + ln31;
    const float biasr  = bi[jc] + bh[jc];
    const float biasz  = bi[64 + jc] + bh[64 + jc];
    const float biasni = bi[128 + jc];
    const float biasnh = bh[128 + jc];
    float w0r = 0.f, w0z = 0.f, w0n = 0.f;
    if (l == 0) { w0r = wih0[jc]; w0z = wih0[64 + jc]; w0n = wih0[128 + jc]; }
    const int ihB = (l - 1) * 48 + jh * 4;                     // l>0 only
    const int hhB = (l == 0) ? (144 + jh * 4) : (ihB + 24);

    // preload hh weight fragments (loop-invariant, 48 VGPRs)
    f16x8 Bhh[12];
    #pragma unroll
    for (int g = 0; g < 3; ++g)
        #pragma unroll
        for (int kt = 0; kt < 4; ++kt)
            Bhh[g * 4 + kt] = load_b(hhB + g * 8 + kt, lane);

    // write addressing for this lane's column jc
    const int chw = jc >> 3, wrd = (jc & 7) >> 1, hv = jc & 1;

    // h(t-1) for this lane's C-fragment cells, fp32
    float hreg[32];
    #pragma unroll
    for (int q = 0; q < 32; ++q) hreg[q] = 0.f;

    // ---------------- pipelined GRU layers ----------------
    for (int i = 0; i <= lv + 2; ++i) {
        const int t = i - l;
        // layer-0 input: consume last iteration's load, issue the next one.
        if (w == 0) {
            const int tn = i + 1;
            if (tn < lv) {
                const float sfc = (r3 == 0) ? s0 : ((r3 == 1) ? s1 : s2);
                const float bpc = (r3 == 0) ? b0 : ((r3 == 1) ? b1 : b2);
                v0F[(tn & 1) * 64 + lane] = fmaf(xv, sfc, bpc);
                r3 = (r3 == 2) ? 0 : r3 + 1;
                if (tn + 1 < lv) xv = x[(n * 24 + tn + 1) * 4096 + vox];
            }
        }
        if (t >= 0 && t < lv) {
            const int pbit = t & 1;
            const unsigned int* hOwn = sm + l * 8192 + (pbit ^ 1) * 4096;
            const unsigned int* hUp  = (l > 0) ? (sm + (l - 1) * 8192 + pbit * 4096) : nullptr;
            unsigned short* hw16 = (unsigned short*)(sm + l * 8192 + pbit * 4096);
            const bool dosel = (l == 3) && (t == lv - 1 || t == lv - 4);

            #pragma unroll
            for (int rt = 0; rt < 2; ++rt) {
                const int rb = rt * 32;
                f32x16 Cr = zero16(), Cz = zero16(), Ci = zero16(), Ch = zero16();

                __builtin_amdgcn_s_setprio(1);
                #pragma unroll
                for (int kt = 0; kt < 4; ++kt) {
                    const int cH = 2 * kt + hl;
                    const f16x8 ah_h = read_frag(hOwn, rb + ln31, cH);
                    const f16x8 ah_l = read_frag(hOwn, rb + ln31, cH | 8);
                    MFMA16(Cr, ah_h, Bhh[kt]);     MFMA16(Cr, ah_l, Bhh[kt]);
                    MFMA16(Cz, ah_h, Bhh[4 + kt]); MFMA16(Cz, ah_l, Bhh[4 + kt]);
                    MFMA16(Ch, ah_h, Bhh[8 + kt]); MFMA16(Ch, ah_l, Bhh[8 + kt]);
                    if (l > 0) {
                        const f16x8 Bri = load_b(ihB + 0  + kt, lane);
                        const f16x8 Bzi = load_b(ihB + 8  + kt, lane);
                        const f16x8 Bni = load_b(ihB + 16 + kt, lane);
                        const f16x8 ax_h = read_frag(hUp, rb + ln31, cH);
                        const f16x8 ax_l = read_frag(hUp, rb + ln31, cH | 8);
                        MFMA16(Cr, ax_h, Bri); MFMA16(Cr, ax_l, Bri);
                        MFMA16(Cz, ax_h, Bzi); MFMA16(Cz, ax_l, Bzi);
                        MFMA16(Ci, ax_h, Bni); MFMA16(Ci, ax_l, Bni);
                    }
                }
                __builtin_amdgcn_s_setprio(0);

                // extract + h update (C layout: col=lane&31, row=(rg&3)+8*(rg>>2)+4*hl)
                #pragma unroll
                for (int rg = 0; rg < 16; ++rg) {
                    const int row = rb + (rg & 3) + ((rg >> 2) << 3) + (hl << 2);
                    const int rsw = row & 15;
                    const int iHi = row * 128 + (((chw ^ rsw) << 2) + wrd) * 2 + hv;
                    const int iLo = iHi ^ 64;
                    float pr = Cr[rg] + biasr;
                    float pz = Cz[rg] + biasz;
                    float pi = Ci[rg] + biasni;
                    float ph = Ch[rg] + biasnh;
                    if (l == 0) {
                        const float v0 = v0F[pbit * 64 + row];
                        pr = fmaf(v0, w0r, pr);
                        pz = fmaf(v0, w0z, pz);
                        pi = fmaf(v0, w0n, pi);
                    }
                    const float r  = sigm(pr);
                    const float z  = sigm(pz);
                    const float nn = tanhfast(fmaf(r, ph, pi));
                    const float hp = hreg[rt * 16 + rg];
                    const float hn = fmaf(z, hp - nn, nn);
                    hreg[rt * 16 + rg] = hn;
                    const __half hhi = __float2half(hn);
                    hw16[iHi] = __half_as_ushort(hhi);
                    hw16[iLo] = __half_as_ushort(__float2half(hn - __half2float(hhi)));
                    if (dosel) selF[row * 68 + jc] += hn;
                }
                __builtin_amdgcn_sched_barrier(0);   // keep tiles sequential (reg pressure)
            }
        }
        BLOCK_SYNC();
    }

    __syncthreads();

    // ---------------- MLP head: 8 waves, 8 cols each ----------------
    float* ybuf = (float*)sm;             // [64][68]
    float* psum = (float*)sm + 64 * 68;   // [8][64]
    const int jb = w * 8;
    float h2[8];
    #pragma unroll
    for (int jj = 0; jj < 8; ++jj) h2[jj] = selF[lane * 68 + jb + jj];

    for (int li = 0; li < 5; ++li) {
        __syncthreads();
        #pragma unroll
        for (int jj = 0; jj < 8; ++jj) {
            const int j = jb + jj;
            const float sc = bng[li * 64 + j] * rsqrtf(bnv[li * 64 + j] + 1e-5f);
            const float y  = fmaf(h2[jj] - bnm[li * 64 + j], sc, bnb[li * 64 + j]);
            ybuf[lane * 68 + j] = y * sigm(y);
        }
        __syncthreads();
        #pragma unroll
        for (int jj = 0; jj < 8; ++jj) {
            const int j = jb + jj;
            float acc = fcb[li * 64 + j];
            const float* wr = fcW + (li * 64 + j) * 64;
            #pragma unroll
            for (int k = 0; k < 64; k += 4) {
                const float4 yv = *reinterpret_cast<const float4*>(ybuf + lane * 68 + k);
                acc = fmaf(yv.x, wr[k],     acc);
                acc = fmaf(yv.y, wr[k + 1], acc);
                acc = fmaf(yv.z, wr[k + 2], acc);
                acc = fmaf(yv.w, wr[k + 3], acc);
            }
            h2[jj] = acc;
        }
    }
    {
        float part = 0.f;
        #pragma unroll
        for (int jj = 0; jj < 8; ++jj) {
            const int j = jb + jj;
            const float sc = bng[5 * 64 + j] * rsqrtf(bnv[5 * 64 + j] + 1e-5f);
            const float y  = fmaf(h2[jj] - bnm[5 * 64 + j], sc, bnb[5 * 64 + j]);
            part = fmaf(y * sigm(y), fcWo[j], part);
        }
        psum[w * 64 + lane] = part;
    }
    __syncthreads();
    if (w == 0) {
        float s = fcbo[0];
        #pragma unroll
        for (int q = 0; q < 8; ++q) s += psum[q * 64 + lane];
        out[(bid << 6) + lane] = s;
    }
}

extern "C" void kernel_launch(void* const* d_in, const int* in_sizes, int n_in,
                              void* d_out, int out_size, void* d_ws, size_t ws_size,
                              hipStream_t stream) {
    (void)in_sizes; (void)n_in; (void)d_ws; (void)ws_size; (void)out_size;
    const float* x    = (const float*)d_in[0];
    const int*   len  = (const int*)d_in[1];
    const float* sf3  = (const float*)d_in[2];
    const float* bp3  = (const float*)d_in[3];
    const float* wih0 = (const float*)d_in[4];
    const float* whh0 = (const float*)d_in[5];
    const float* bih0 = (const float*)d_in[6];
    const float* bhh0 = (const float*)d_in[7];
    const float* wihs = (const float*)d_in[8];
    const float* whhs = (const float*)d_in[9];
    const float* bihs = (const float*)d_in[10];
    const float* bhhs = (const float*)d_in[11];
    const float* bng  = (const float*)d_in[12];
    const float* bnb  = (const float*)d_in[13];
    const float* bnm  = (const float*)d_in[14];
    const float* bnv  = (const float*)d_in[15];
    const float* fcW  = (const float*)d_in[16];
    const float* fcb  = (const float*)d_in[17];
    const float* fcWo = (const float*)d_in[18];
    const float* fcbo = (const float*)d_in[19];
    float* out = (float*)d_out;

    prep_wfrag<<<dim3(42), dim3(256), 0, stream>>>(whh0, wihs, whhs);
    gru_mfma<<<dim3(256), dim3(512), 0, stream>>>(
        x, len, sf3, bp3, wih0, bih0, bhh0, bihs, bhhs,
        bng, bnb, bnm, bnv, fcW, fcb, fcWo, fcbo, out);
}